// Round 11
// baseline (4847.289 us; speedup 1.0000x reference)
//
#include <hip/hip_runtime.h>
#include <hip/hip_bf16.h>
#include <math.h>

// Problem constants: T=512, B=64, D=512, H=1024, O=512
constexpr int T = 512;
constexpr int B = 64;
constexpr int D = 512;
constexpr int H = 1024;
constexpr int O = 512;
constexpr int GROUPS = 2;          // independent batch groups (no cross-sync)
constexpr int BG   = B / GROUPS;   // 32 batch rows per group
constexpr int GBLK = 128;          // blocks per group (own the 4096 gate-cols)
constexpr int COLS = 32;           // gate-cols per block
constexpr int KCH  = (D + H) / 8;  // 192 k-chunks of 8 elems

typedef __attribute__((ext_vector_type(8))) __bf16 bf16x8;
typedef __attribute__((ext_vector_type(4))) float  floatx4;

// Packed arrival flags, one dword per block (R19-proven).
struct GBar {
    unsigned arr[GBLK];   // flag[gb] = t+1 once block gb finished step t
};

// ---------------------------------------------------------------------------
// W' bf16, strip-major: Wc[strip(128)][kchunk(192)][nl(32)][8]. (R14 layout)
// Column reorder: nl -> s=nl>>4, jl=(nl>>2)&3, g=nl&3 ; j = gb*8 + 2*jl + s.
// k<512 from Wx[g*H+j][k], else Wh[g*H+j][k-512].
// ---------------------------------------------------------------------------
__global__ __launch_bounds__(256) void convert_w(
    const float* __restrict__ Wx, const float* __restrict__ Wh,
    __bf16* __restrict__ Wc)
{
    const int id = blockIdx.x * 256 + threadIdx.x;   // 128*192*32 = 786432
    if (id >= GBLK * KCH * COLS) return;
    const int nl     = id & 31;
    const int kchunk = (id >> 5) % KCH;
    const int strip  = id / (KCH * COLS);
    const int s  = nl >> 4;
    const int jl = (nl >> 2) & 3;
    const int g  = nl & 3;
    const int j  = strip * 8 + 2 * jl + s;
    const int k0 = kchunk * 8;
    const float* src = (k0 < D) ? &Wx[(size_t)(g * H + j) * D + k0]
                                : &Wh[(size_t)(g * H + j) * H + (k0 - D)];
    const float4 a = *(const float4*)src;
    const float4 b = *(const float4*)(src + 4);
    __bf16 t8[8] = {(__bf16)a.x,(__bf16)a.y,(__bf16)a.z,(__bf16)a.w,
                    (__bf16)b.x,(__bf16)b.y,(__bf16)b.z,(__bf16)b.w};
    *(uint4*)&Wc[(size_t)id * 8] = *(uint4*)t8;
}

__global__ __launch_bounds__(256) void make_bias(
    const float* __restrict__ bx, const float* __restrict__ bh,
    float* __restrict__ bias)
{
    const int n = blockIdx.x * 256 + threadIdx.x;
    if (n < 4 * H) {
        const int gbn = n >> 5, nl = n & 31;
        const int s  = nl >> 4;
        const int jl = (nl >> 2) & 3;
        const int g  = nl & 3;
        const int j  = gbn * 8 + 2 * jl + s;
        bias[n] = bx[g * H + j] + bh[g * H + j];
    }
}

// ---------------------------------------------------------------------------
// Persistent LSTM, round 25 = R19 core (identical math) + DATAFLOW-CHUNKED
// burst via LDS readiness flags:
//  - wave 2 = poller: reads the 128 packed flags (dwordx2/lane, ballot),
//    publishes sflag[s]=t to LDS when producers 32s..32s+31 arrived; does
//    the arrive store after the step barrier.
//  - waves 0/1 = compute: ONE asm block per step:
//      4 x { LDS-spin on sflag[s] (ds_read_b32 + lgkmcnt(0) — orthogonal to
//            vmcnt, so in-flight h-loads are NOT drained) ; 8 h-loads }
//      then one final vmcnt(0).
//    Early chunks' loads stream from L3 while late producers arrive; after
//    the last arrival only ~8 loads remain. Compute waves no longer touch
//    global flags (poll traffic halves).
//  - chunk sg covers h-cols [32sg,32sg+32) = producers gb 4sg..4sg+3, so
//    split s (chunks 8s..8s+7) needs exactly flags 32s..32s+31. Passing
//    split 3 <=> all 128 flags >= t: WAR store-gate identical to R19.
//  MFMA order unchanged -> bit-identical results (absmax 0.00390625).
// ---------------------------------------------------------------------------
__global__ __launch_bounds__(192, 1) void lstm_persistent(
    const float* __restrict__ x,     // [T,B,D] fp32
    const __bf16* __restrict__ Wc,   // strip-major bf16 (read once at start)
    const float* __restrict__ bias,  // [4096] reordered
    __bf16* __restrict__ hbufs,      // [GROUPS][2][BG*H] bf16 ping/pong
    float* __restrict__ hfin,        // [B,H] fp32 final h (aliases Wc head)
    GBar* bars)                      // [GROUPS]
{
    __shared__ __attribute__((aligned(16))) __bf16 wlds[KCH * COLS * 8]; // 96 KB
    __shared__ int sflag[4];         // per-split readiness (step number)

    const int tid   = threadIdx.x;
    const int wid   = tid >> 6;    // 0,1 = compute m-tiles; 2 = poller
    const int lane  = tid & 63;
    const int cm    = lane & 15;
    const int q     = lane >> 4;
    const int group = blockIdx.x >> 7;          // 0..1
    const int gb    = blockIdx.x & 127;         // block within group
    const int n0    = gb * COLS;
    GBar* bar = bars + group;
    __bf16* hb0 = hbufs + (size_t)group * 2 * BG * H;
    __bf16* hb1 = hb0 + BG * H;

    // ---- one-time: W strip -> LDS (6144 x 16B contiguous) ----
    {
        const uint4* wsrc = (const uint4*)(Wc + (size_t)gb * KCH * COLS * 8);
        uint4* wdst = (uint4*)wlds;
        for (int i = tid; i < KCH * COLS; i += 192) wdst[i] = wsrc[i];
    }
    if (tid < 4) sflag[tid] = -1;
    __syncthreads();

    if (wid == 2) {
        // ================= poller wave =================
        const unsigned* fp = bar->arr + 2 * lane;   // 2 packed flags per lane
        for (int t = 0; t < T; ++t) {
            const int want = t;
            for (;;) {
                uint2 fv;
                asm volatile("global_load_dwordx2 %0, %1, off sc0 sc1\n\t"
                             "s_waitcnt vmcnt(0)"
                             : "=v"(fv) : "v"(fp) : "memory");
                const int mn = (int)(fv.x < fv.y ? fv.x : fv.y);
                const unsigned long long b = __ballot(mn >= want);
                if (lane < 4 &&
                    (((b >> (16 * lane)) & 0xFFFFull) == 0xFFFFull))
                    ((volatile int*)sflag)[lane] = want;
                if (b == ~0ull) break;
                __builtin_amdgcn_s_sleep(1);
            }
            __syncthreads();   // compute h-stores drained at barrier entry
            if (lane == 0)
                __hip_atomic_store(&bar->arr[gb], (unsigned)(t + 1),
                                   __ATOMIC_RELAXED, __HIP_MEMORY_SCOPE_AGENT);
        }
        return;
    }

    // ================= compute waves (wid 0/1) =================
    const int p4 = cm & 3;
    const int jl = cm >> 2;
    const int row_l = wid * 16 + q * 4 + p4;     // 0..31 local batch row
    const float4 bias0q = *(const float4*)&bias[n0 + jl * 4];        // strip 0
    const float4 bias1q = *(const float4*)&bias[n0 + 16 + jl * 4];   // strip 1
    float c0 = 0.f, c1 = 0.f;

    const int grow = group * BG + wid * 16 + cm;
    const float* xrow = x + (size_t)grow * D + q * 8;
    const int    hoff = (wid * 16 + cm) * H + q * 8;   // within group h buffer
    const __bf16* wl  = wlds + (q * 32 + cm) * 8;
    const unsigned sfa = (unsigned)(size_t)(&sflag[0]); // LDS byte offset

    floatx4 acc[2][2];   // [col-strip][k-parity]
    float4  xcur[16][2]; // prefetched x_t fragments

    auto loadx = [&](int tt) {
        const float* xr = xrow + (size_t)tt * (B * D);
        #pragma unroll
        for (int s = 0; s < 16; ++s) {
            xcur[s][0] = *(const float4*)(xr + s * 32);
            xcur[s][1] = *(const float4*)(xr + s * 32 + 4);
        }
    };
    auto xmfma = [&]() {
        acc[0][0] = (floatx4){0,0,0,0}; acc[0][1] = (floatx4){0,0,0,0};
        acc[1][0] = (floatx4){0,0,0,0}; acc[1][1] = (floatx4){0,0,0,0};
        #pragma unroll
        for (int s = 0; s < 16; ++s) {
            const float4 a0 = xcur[s][0], a1 = xcur[s][1];
            const bf16x8 af = {(__bf16)a0.x,(__bf16)a0.y,(__bf16)a0.z,(__bf16)a0.w,
                               (__bf16)a1.x,(__bf16)a1.y,(__bf16)a1.z,(__bf16)a1.w};
            const bf16x8 b0 = *(const bf16x8*)(wl + s * 1024);
            const bf16x8 b1 = *(const bf16x8*)(wl + s * 1024 + 128);
            acc[0][s & 1] = __builtin_amdgcn_mfma_f32_16x16x32_bf16(af, b0, acc[0][s & 1], 0, 0, 0);
            acc[1][s & 1] = __builtin_amdgcn_mfma_f32_16x16x32_bf16(af, b1, acc[1][s & 1], 0, 0, 0);
        }
    };

    // 4x4 transpose across lane-quads (R13-verified butterfly)
    auto quadT = [&](float v[4]) {
        float w0 = __shfl_xor(v[1], 1), w1 = __shfl_xor(v[0], 1);
        float w2 = __shfl_xor(v[3], 1), w3 = __shfl_xor(v[2], 1);
        if (p4 & 1) { v[0] = w0; v[2] = w2; } else { v[1] = w1; v[3] = w3; }
        w0 = __shfl_xor(v[2], 2); w1 = __shfl_xor(v[3], 2);
        w2 = __shfl_xor(v[0], 2); w3 = __shfl_xor(v[1], 2);
        if (p4 & 2) { v[0] = w0; v[1] = w1; } else { v[2] = w2; v[3] = w3; }
    };

    loadx(0);
    xmfma();

    for (int t = 0; t < T; ++t) {
        const __bf16* hcur = (t & 1) ? hb1 : hb0;
        __bf16*       hnxt = (t & 1) ? hb0 : hb1;

        // ---- h-part: 4 x { LDS-spin(split ready) ; 8 chunk loads }, then
        //      ONE final vmcnt(0). LDS spins use lgkmcnt only -> in-flight
        //      h-loads keep streaming while later producers arrive. ----
        {
            const __bf16* hbase = hcur + hoff;   // per-lane, 16B aligned
            uint4 hv[32];
            unsigned ftmp;
            asm volatile(
                // split 0: sflag[0] -> chunks 0..7
                "1: ds_read_b32 %[f], %[sa]\n\t"
                "s_waitcnt lgkmcnt(0)\n\t"
                "v_cmp_gt_i32 vcc, %[tt], %[f]\n\t"
                "s_cbranch_vccnz 1b\n\t"
                "global_load_dwordx4 %[h0], %[hb], off sc0 sc1\n\t"
                "global_load_dwordx4 %[h1], %[hb], off offset:64 sc0 sc1\n\t"
                "global_load_dwordx4 %[h2], %[hb], off offset:128 sc0 sc1\n\t"
                "global_load_dwordx4 %[h3], %[hb], off offset:192 sc0 sc1\n\t"
                "global_load_dwordx4 %[h4], %[hb], off offset:256 sc0 sc1\n\t"
                "global_load_dwordx4 %[h5], %[hb], off offset:320 sc0 sc1\n\t"
                "global_load_dwordx4 %[h6], %[hb], off offset:384 sc0 sc1\n\t"
                "global_load_dwordx4 %[h7], %[hb], off offset:448 sc0 sc1\n\t"
                // split 1: sflag[1] -> chunks 8..15
                "1: ds_read_b32 %[f], %[sa] offset:4\n\t"
                "s_waitcnt lgkmcnt(0)\n\t"
                "v_cmp_gt_i32 vcc, %[tt], %[f]\n\t"
                "s_cbranch_vccnz 1b\n\t"
                "global_load_dwordx4 %[h8], %[hb], off offset:512 sc0 sc1\n\t"
                "global_load_dwordx4 %[h9], %[hb], off offset:576 sc0 sc1\n\t"
                "global_load_dwordx4 %[h10], %[hb], off offset:640 sc0 sc1\n\t"
                "global_load_dwordx4 %[h11], %[hb], off offset:704 sc0 sc1\n\t"
                "global_load_dwordx4 %[h12], %[hb], off offset:768 sc0 sc1\n\t"
                "global_load_dwordx4 %[h13], %[hb], off offset:832 sc0 sc1\n\t"
                "global_load_dwordx4 %[h14], %[hb], off offset:896 sc0 sc1\n\t"
                "global_load_dwordx4 %[h15], %[hb], off offset:960 sc0 sc1\n\t"
                // split 2: sflag[2] -> chunks 16..23
                "1: ds_read_b32 %[f], %[sa] offset:8\n\t"
                "s_waitcnt lgkmcnt(0)\n\t"
                "v_cmp_gt_i32 vcc, %[tt], %[f]\n\t"
                "s_cbranch_vccnz 1b\n\t"
                "global_load_dwordx4 %[h16], %[hb], off offset:1024 sc0 sc1\n\t"
                "global_load_dwordx4 %[h17], %[hb], off offset:1088 sc0 sc1\n\t"
                "global_load_dwordx4 %[h18], %[hb], off offset:1152 sc0 sc1\n\t"
                "global_load_dwordx4 %[h19], %[hb], off offset:1216 sc0 sc1\n\t"
                "global_load_dwordx4 %[h20], %[hb], off offset:1280 sc0 sc1\n\t"
                "global_load_dwordx4 %[h21], %[hb], off offset:1344 sc0 sc1\n\t"
                "global_load_dwordx4 %[h22], %[hb], off offset:1408 sc0 sc1\n\t"
                "global_load_dwordx4 %[h23], %[hb], off offset:1472 sc0 sc1\n\t"
                // split 3: sflag[3] -> chunks 24..31
                "1: ds_read_b32 %[f], %[sa] offset:12\n\t"
                "s_waitcnt lgkmcnt(0)\n\t"
                "v_cmp_gt_i32 vcc, %[tt], %[f]\n\t"
                "s_cbranch_vccnz 1b\n\t"
                "global_load_dwordx4 %[h24], %[hb], off offset:1536 sc0 sc1\n\t"
                "global_load_dwordx4 %[h25], %[hb], off offset:1600 sc0 sc1\n\t"
                "global_load_dwordx4 %[h26], %[hb], off offset:1664 sc0 sc1\n\t"
                "global_load_dwordx4 %[h27], %[hb], off offset:1728 sc0 sc1\n\t"
                "global_load_dwordx4 %[h28], %[hb], off offset:1792 sc0 sc1\n\t"
                "global_load_dwordx4 %[h29], %[hb], off offset:1856 sc0 sc1\n\t"
                "global_load_dwordx4 %[h30], %[hb], off offset:1920 sc0 sc1\n\t"
                "global_load_dwordx4 %[h31], %[hb], off offset:1984 sc0 sc1\n\t"
                "s_waitcnt vmcnt(0)"
                : [h0]"=&v"(hv[0]),  [h1]"=&v"(hv[1]),  [h2]"=&v"(hv[2]),  [h3]"=&v"(hv[3]),
                  [h4]"=&v"(hv[4]),  [h5]"=&v"(hv[5]),  [h6]"=&v"(hv[6]),  [h7]"=&v"(hv[7]),
                  [h8]"=&v"(hv[8]),  [h9]"=&v"(hv[9]),  [h10]"=&v"(hv[10]), [h11]"=&v"(hv[11]),
                  [h12]"=&v"(hv[12]), [h13]"=&v"(hv[13]), [h14]"=&v"(hv[14]), [h15]"=&v"(hv[15]),
                  [h16]"=&v"(hv[16]), [h17]"=&v"(hv[17]), [h18]"=&v"(hv[18]), [h19]"=&v"(hv[19]),
                  [h20]"=&v"(hv[20]), [h21]"=&v"(hv[21]), [h22]"=&v"(hv[22]), [h23]"=&v"(hv[23]),
                  [h24]"=&v"(hv[24]), [h25]"=&v"(hv[25]), [h26]"=&v"(hv[26]), [h27]"=&v"(hv[27]),
                  [h28]"=&v"(hv[28]), [h29]"=&v"(hv[29]), [h30]"=&v"(hv[30]), [h31]"=&v"(hv[31]),
                  [f]"=&v"(ftmp)
                : [hb]"v"(hbase), [sa]"v"(sfa), [tt]"v"(t)
                : "memory", "vcc");
            #pragma unroll
            for (int sg = 0; sg < 32; ++sg) {
                union { uint4 u; bf16x8 v; } hf; hf.u = hv[sg];
                const bf16x8 b0 = *(const bf16x8*)(wl + 16384 + sg * 1024);
                const bf16x8 b1 = *(const bf16x8*)(wl + 16384 + sg * 1024 + 128);
                acc[0][sg & 1] = __builtin_amdgcn_mfma_f32_16x16x32_bf16(hf.v, b0, acc[0][sg & 1], 0, 0, 0);
                acc[1][sg & 1] = __builtin_amdgcn_mfma_f32_16x16x32_bf16(hf.v, b1, acc[1][sg & 1], 0, 0, 0);
            }
        }
        const floatx4 av0 = acc[0][0] + acc[0][1];
        const floatx4 av1 = acc[1][0] + acc[1][1];

        // ---- in-register quad transpose ----
        float g0v[4] = {av0.x, av0.y, av0.z, av0.w};
        float g1v[4] = {av1.x, av1.y, av1.z, av1.w};
        quadT(g0v);
        quadT(g1v);

        // ---- prefetch x for t+1 (RTT hides under the cell update) ----
        if (t + 1 < T) loadx(t + 1);

        // ---- fused cell update: lane owns (row_l, j0) and (row_l, j0+1) ----
        const float i0 = 1.f / (1.f + expf(-(g0v[0] + bias0q.x)));
        const float f0 = 1.f / (1.f + expf(-(g0v[1] + bias0q.y)));
        const float o0 = 1.f / (1.f + expf(-(g0v[2] + bias0q.z)));
        const float t0 = tanhf(g0v[3] + bias0q.w);
        const float i1 = 1.f / (1.f + expf(-(g1v[0] + bias1q.x)));
        const float f1 = 1.f / (1.f + expf(-(g1v[1] + bias1q.y)));
        const float o1 = 1.f / (1.f + expf(-(g1v[2] + bias1q.z)));
        const float t1 = tanhf(g1v[3] + bias1q.w);
        c0 = f0 * c0 + i0 * t0;
        c1 = f1 * c1 + i1 * t1;
        const float hv0 = o0 * tanhf(c0);
        const float hv1 = o1 * tanhf(c1);
        const int j0 = gb * 8 + 2 * jl;      // even local j; pair (j0, j0+1)
        const int hi = row_l * H + j0;
        union { __bf16 h2[2]; unsigned u; } hp;
        hp.h2[0] = (__bf16)hv0; hp.h2[1] = (__bf16)hv1;
        __hip_atomic_store((unsigned*)&hnxt[hi], hp.u, __ATOMIC_RELAXED,
                           __HIP_MEMORY_SCOPE_AGENT);   // one 4B write-through
        if (t == T - 1) {
            const int gr = group * BG + row_l;
            hfin[gr * H + j0]     = hv0;
            hfin[gr * H + j0 + 1] = hv1;
        }

        __syncthreads();  // drain h stores (vmcnt0); poller then arrives

        // ---- x MFMAs for t+1 in the propagation shadow ----
        if (t + 1 < T) xmfma();
    }
}

// out[b,o] = h[b,:] . Why[o,:] + bhy[o]
__global__ __launch_bounds__(256) void out_gemm(
    const float* __restrict__ h, const float* __restrict__ Why,
    const float* __restrict__ bhy, float* __restrict__ out)
{
    const int idx = blockIdx.x * 256 + threadIdx.x;
    if (idx >= B * O) return;
    const int b = idx / O;
    const int o = idx % O;
    const float4* hv = (const float4*)&h[(size_t)b * H];
    const float4* wv = (const float4*)&Why[(size_t)o * H];
    float s = 0.f;
    #pragma unroll 4
    for (int k = 0; k < H / 4; ++k) {
        const float4 a = hv[k];
        const float4 w = wv[k];
        s += a.x * w.x + a.y * w.y + a.z * w.z + a.w * w.w;
    }
    out[idx] = s + bhy[o];
}

extern "C" void kernel_launch(void* const* d_in, const int* in_sizes, int n_in,
                              void* d_out, int out_size, void* d_ws, size_t ws_size,
                              hipStream_t stream) {
    const float* x   = (const float*)d_in[0];
    const float* Wx  = (const float*)d_in[1];
    const float* bx  = (const float*)d_in[2];
    const float* Wh  = (const float*)d_in[3];
    const float* bh  = (const float*)d_in[4];
    const float* Why = (const float*)d_in[5];
    const float* bhy = (const float*)d_in[6];
    float* out = (float*)d_out;

    // ws layout (~12.86 MB total, <= proven 12.90 MB):
    // Wc 12,582,912 | bias 16,384 @12,582,912 | hbufs 262,144 @12,599,296
    // bars 2 x 512 @12,861,440 (packed flags)
    // hfin (256 KB fp32) aliases Wc[0:262144) — Wc only read during the
    // one-time LDS stage, 511 barriers before any t=T-1 write. Safe.
    char* ws = (char*)d_ws;
    __bf16* Wc    = (__bf16*)ws;
    float*  bias  = (float*)(ws + 12582912);
    __bf16* hbufs = (__bf16*)(ws + 12599296);   // [2][2][BG*H] = 256 KB
    GBar*   bars  = (GBar*)  (ws + 12861440);   // 2 x 512 B (packed flags)
    float*  hfin  = (float*)ws;

    (void)hipMemsetAsync(ws + 12599296, 0, 262144 + 2 * sizeof(GBar), stream);
    convert_w<<<3072, 256, 0, stream>>>(Wx, Wh, Wc);
    make_bias<<<16, 256, 0, stream>>>(bx, bh, bias);

    lstm_persistent<<<GROUPS * GBLK, 192, 0, stream>>>(x, Wc, bias, hbufs,
                                                       hfin, bars);

    out_gemm<<<(B * O + 255) / 256, 256, 0, stream>>>(hfin, Why, bhy, out);
}